// Round 9
// baseline (644.335 us; speedup 1.0000x reference)
//
#include <hip/hip_runtime.h>
#include <math.h>

#define N_NODES 100000
#define N_EDGES 3200000
#define F_IN    512
#define HID     16
#define NCLS    7
#define ALPHA   0.1f
#define K_HOPS  10

// bucketing: 128 nodes per bucket, fixed per-bucket slab (no histogram/scan pass)
#define SHIFT   7
#define BWIDTH  128
#define NBUCK   ((N_NODES + BWIDTH - 1) / BWIDTH)   // 782
#define SLAB    5120        // capacity per bucket: mean 4096 + 16 sigma (uniform dst)
#define CHUNK   4096
#define BIN_T   512
#define EPT     (CHUNK / BIN_T)                      // 8
#define A3_BLOCKS ((N_EDGES + CHUNK - 1) / CHUNK)   // 782

// ---- workspace layout (4-byte element offsets); no aliasing ----
#define OFF_BCUR    0u          // int[782]   per-bucket fill counters (memset 0)
#define OFF_RP      1024u       // int[100000] slab-global edge start per node
#define OFF_DEG     101376u     // int[100000]
#define OFF_DINV    201728u     // float[100000]
#define OFF_COL     302080u     // int[782*5120 = 4003840]
#define OFF_BINNED  4305920u    // uint[4003840]
#define OFF_H0      8309760u    // float[100000*16]
#define OFF_Z       9909760u    // float[100000*8]
// total = 10709760 elems = 42.8 MB

// ---------------- bin: slab append of packed edges (no histogram pass) ----------------
// binned[b*SLAB + pos] = (dst&127)<<17 | src
__global__ void __launch_bounds__(BIN_T)
k_bin(const int* __restrict__ src, const int* __restrict__ dst,
      int* __restrict__ bcur, unsigned int* __restrict__ binned) {
    __shared__ int ha[NBUCK];
    __shared__ int gbase[NBUCK];
    __shared__ int lcur[NBUCK];
    int tid = threadIdx.x;
    int e0 = blockIdx.x * CHUNK;
    int e1 = e0 + CHUNK;
    if (e1 > N_EDGES) e1 = N_EDGES;
    for (int i = tid; i < NBUCK; i += BIN_T) ha[i] = 0;
    __syncthreads();
    int dloc[EPT];
#pragma unroll
    for (int i = 0; i < EPT; i++) {
        int e = e0 + tid + i * BIN_T;
        dloc[i] = (e < e1) ? dst[e] : -1;
        if (dloc[i] >= 0) atomicAdd(&ha[dloc[i] >> SHIFT], 1);
    }
    __syncthreads();
    for (int s = tid; s < NBUCK; s += BIN_T) {
        int c = ha[s];
        lcur[s] = 0;
        gbase[s] = c ? (s * SLAB + atomicAdd(&bcur[s], c)) : 0;
    }
    __syncthreads();
#pragma unroll
    for (int i = 0; i < EPT; i++) {
        int d = dloc[i];
        if (d >= 0) {
            int e = e0 + tid + i * BIN_T;
            int bk = d >> SHIFT;
            int idx = atomicAdd(&lcur[bk], 1);
            binned[gbase[bk] + idx] =
                ((unsigned int)(d & (BWIDTH - 1)) << 17) | (unsigned int)src[e];
        }
    }
}

// ---------------- csr: per-bucket count, local scan, rp/deg/dinv, col scatter ----------------
__global__ void __launch_bounds__(512)
k_csr(const unsigned int* __restrict__ binned, const int* __restrict__ bcur,
      int* __restrict__ rp, int* __restrict__ deg, float* __restrict__ dinv,
      int* __restrict__ col) {
    __shared__ int cnt[BWIDTH];
    __shared__ int s[BWIDTH];
    __shared__ int cur[BWIDTH];
    int tid = threadIdx.x;
    int b = blockIdx.x;
    int base = b << SHIFT;
    int e0 = b * SLAB;
    int e1 = e0 + bcur[b];
    if (tid < BWIDTH) cnt[tid] = 0;
    __syncthreads();
    for (int e = e0 + tid; e < e1; e += 512)
        atomicAdd(&cnt[binned[e] >> 17], 1);
    __syncthreads();
    int v = 0;
    if (tid < BWIDTH) { v = cnt[tid]; s[tid] = v; }
    __syncthreads();
    for (int off = 1; off < BWIDTH; off <<= 1) {
        int t = 0;
        if (tid < BWIDTH && tid >= off) t = s[tid - off];
        __syncthreads();
        if (tid < BWIDTH) s[tid] += t;
        __syncthreads();
    }
    if (tid < BWIDTH) {
        int ex = s[tid] - v;
        cur[tid] = ex;
        int node = base + tid;
        if (node < N_NODES) {
            rp[node] = e0 + ex;
            deg[node] = v;
            dinv[node] = rsqrtf((float)(v + 1));
        }
    }
    __syncthreads();
    for (int e = e0 + tid; e < e1; e += 512) {
        unsigned int w = binned[e];
        int ln = (int)(w >> 17);
        int p = atomicAdd(&cur[ln], 1);
        col[e0 + p] = (int)(w & 0x1FFFFu);
    }
}

// ---------------- h0s = dinv * (x @ W1): wave-per-node, 2-deep prefetch ----------------
#define XWN_BLOCKS 512
#define XWN_WAVES  (XWN_BLOCKS * 4)   // 2048

__device__ __forceinline__ float4 shfl4_xor(float4 v, int m) {
    float4 r;
    r.x = __shfl_xor(v.x, m);
    r.y = __shfl_xor(v.y, m);
    r.z = __shfl_xor(v.z, m);
    r.w = __shfl_xor(v.w, m);
    return r;
}
__device__ __forceinline__ float4 add4(float4 a, float4 b) {
    a.x += b.x; a.y += b.y; a.z += b.z; a.w += b.w;
    return a;
}

__global__ void __launch_bounds__(256)
k_xw1(const float* __restrict__ x, const float* __restrict__ W,
      const float* __restrict__ dinv, float* __restrict__ h0s) {
    int lane = threadIdx.x & 63;
    int wid = (blockIdx.x * 256 + threadIdx.x) >> 6;   // 0..2047

    // W rows 8*lane .. 8*lane+7, all 16 cols -> 32 float4 regs
    float4 w[32];
    const float4* W4 = (const float4*)W;
#pragma unroll
    for (int j = 0; j < 8; j++) {
#pragma unroll
        for (int q = 0; q < 4; q++)
            w[j * 4 + q] = W4[(8 * lane + j) * 4 + q];
    }

    int node = wid;
    float4 xc0, xc1, xn0, xn1;
    if (node < N_NODES) {
        const float4* xr = (const float4*)(x + (size_t)node * F_IN) + 2 * lane;
        xc0 = xr[0];
        xc1 = xr[1];
    }
    int n1 = node + XWN_WAVES;
    if (n1 < N_NODES) {
        const float4* xr = (const float4*)(x + (size_t)n1 * F_IN) + 2 * lane;
        xn0 = xr[0];
        xn1 = xr[1];
    }

    for (; node < N_NODES; node += XWN_WAVES) {
        // prefetch node+2*stride (2-deep: ~2 compute bodies cover HBM latency)
        int n2 = node + 2 * XWN_WAVES;
        float4 xp0, xp1;
        if (n2 < N_NODES) {
            const float4* xr = (const float4*)(x + (size_t)n2 * F_IN) + 2 * lane;
            xp0 = xr[0];
            xp1 = xr[1];
        }

        float xa0 = xc0.x, xa1 = xc0.y, xa2 = xc0.z, xa3 = xc0.w;
        float xa4 = xc1.x, xa5 = xc1.y, xa6 = xc1.z, xa7 = xc1.w;

        float4 pp0 = make_float4(0.f, 0.f, 0.f, 0.f);
        float4 pp1 = pp0, pp2 = pp0, pp3 = pp0;
#define XW_FMA(J, XA)                                            \
        pp0.x += XA * w[J*4+0].x; pp0.y += XA * w[J*4+0].y;      \
        pp0.z += XA * w[J*4+0].z; pp0.w += XA * w[J*4+0].w;      \
        pp1.x += XA * w[J*4+1].x; pp1.y += XA * w[J*4+1].y;      \
        pp1.z += XA * w[J*4+1].z; pp1.w += XA * w[J*4+1].w;      \
        pp2.x += XA * w[J*4+2].x; pp2.y += XA * w[J*4+2].y;      \
        pp2.z += XA * w[J*4+2].z; pp2.w += XA * w[J*4+2].w;      \
        pp3.x += XA * w[J*4+3].x; pp3.y += XA * w[J*4+3].y;      \
        pp3.z += XA * w[J*4+3].z; pp3.w += XA * w[J*4+3].w;
        XW_FMA(0, xa0) XW_FMA(1, xa1) XW_FMA(2, xa2) XW_FMA(3, xa3)
        XW_FMA(4, xa4) XW_FMA(5, xa5) XW_FMA(6, xa6) XW_FMA(7, xa7)
#undef XW_FMA

        // reduce-scatter butterfly: c bit3..bit0 = lane bit5..bit2
        int b5 = (lane >> 5) & 1;
        float4 k0 = b5 ? pp2 : pp0;
        float4 k1 = b5 ? pp3 : pp1;
        float4 s0 = b5 ? pp0 : pp2;
        float4 s1 = b5 ? pp1 : pp3;
        k0 = add4(k0, shfl4_xor(s0, 32));
        k1 = add4(k1, shfl4_xor(s1, 32));

        int b4 = (lane >> 4) & 1;
        float4 kk = b4 ? k1 : k0;
        float4 ss = b4 ? k0 : k1;
        kk = add4(kk, shfl4_xor(ss, 16));

        int b3 = (lane >> 3) & 1;
        float e0 = b3 ? kk.z : kk.x;
        float e1 = b3 ? kk.w : kk.y;
        float f0 = b3 ? kk.x : kk.z;
        float f1 = b3 ? kk.y : kk.w;
        e0 += __shfl_xor(f0, 8);
        e1 += __shfl_xor(f1, 8);

        int b2 = (lane >> 2) & 1;
        float v = b2 ? e1 : e0;
        float sv = b2 ? e0 : e1;
        v += __shfl_xor(sv, 4);

        v += __shfl_xor(v, 1);
        v += __shfl_xor(v, 2);

        if ((lane & 3) == 0) {
            float dv = dinv[node];
            h0s[(size_t)node * HID + (lane >> 2)] = dv * v;
        }

        xc0 = xn0; xc1 = xn1;
        xn0 = xp0; xn1 = xp1;
    }
}

// ---------------- aggregate 1 + 10 hops + W2 projection (fused) ----------------
// Wave per node.  After the agg butterfly all 64 lanes hold h[c] (c = lane&15,
// 4 replicas).  Hops run wave-parallel: lane c keeps tm chain in identical
// k-order (bitwise same as the old per-thread k_hops); h[k] broadcast via shfl
// within each 16-lane group.  zs written directly; h1 never materialized.
__global__ void k_agg1hops(const float* __restrict__ h0s, const int* __restrict__ rp,
                           const int* __restrict__ deg, const int* __restrict__ col,
                           const float* __restrict__ dinv, const float* __restrict__ b1,
                           const float* __restrict__ Wl, const float* __restrict__ bl,
                           const float* __restrict__ W2, float* __restrict__ zs) {
    int node = (blockIdx.x * blockDim.x + threadIdx.x) >> 6;
    if (node >= N_NODES) return;
    int lane = threadIdx.x & 63;
    int c = lane & 15, eo = lane >> 4;
    int e0 = rp[node], e1 = e0 + deg[node];
    float acc = 0.f;
    int e = e0 + eo;
    for (; e + 12 < e1; e += 16) {
        int c0 = col[e];
        int c1 = col[e + 4];
        int c2 = col[e + 8];
        int c3 = col[e + 12];
        float v0 = h0s[(size_t)c0 * HID + c];
        float v1 = h0s[(size_t)c1 * HID + c];
        float v2 = h0s[(size_t)c2 * HID + c];
        float v3 = h0s[(size_t)c3 * HID + c];
        acc += v0;
        acc += v1;
        acc += v2;
        acc += v3;
    }
    for (; e + 4 < e1; e += 8) {
        int c0 = col[e];
        int c1 = col[e + 4];
        float v0 = h0s[(size_t)c0 * HID + c];
        float v1 = h0s[(size_t)c1 * HID + c];
        acc += v0;
        acc += v1;
    }
    if (e < e1) acc += h0s[(size_t)col[e] * HID + c];
    acc += __shfl_xor(acc, 16);
    acc += __shfl_xor(acc, 32);       // all 64 lanes now hold the full sum for c

    float dv = dinv[node];
    float o = dv * (acc + h0s[(size_t)node * HID + c]) + b1[c];
    float h = fmaxf(o, 0.f);

    int bs = lane & 48;               // 16-lane group base
    for (int it = 0; it < K_HOPS; it++) {
        float tm = bl[c];
#pragma unroll
        for (int k = 0; k < HID; k++) {
            float hk = __shfl(h, bs + k);
            tm += hk * Wl[k * HID + c];
        }
        h = ALPHA * fmaxf(tm, 0.f) + (1.f - ALPHA) * h;
    }

    float zz = 0.f;
#pragma unroll
    for (int k = 0; k < HID; k++) {
        float hk = __shfl(h, bs + k);
        float w2v = (c < NCLS) ? W2[k * NCLS + c] : 0.f;
        zz += hk * w2v;
    }
    if (eo == 0 && c < 8) zs[(size_t)node * 8 + c] = dv * zz;   // c==7 -> 0
}

// ---------------- aggregate 2 + log_softmax: one wave per node, x4 unroll ----------------
__global__ void k_agg2(const float* __restrict__ zs, const int* __restrict__ rp,
                       const int* __restrict__ deg, const int* __restrict__ col,
                       const float* __restrict__ dinv, const float* __restrict__ b2,
                       float* __restrict__ out) {
    int node = (blockIdx.x * blockDim.x + threadIdx.x) >> 6;
    if (node >= N_NODES) return;
    int lane = threadIdx.x & 63;
    int c = lane & 7, eo = lane >> 3;
    int e0 = rp[node], e1 = e0 + deg[node];
    float acc = 0.f;
    int e = e0 + eo;
    for (; e + 24 < e1; e += 32) {
        int c0 = col[e];
        int c1 = col[e + 8];
        int c2 = col[e + 16];
        int c3 = col[e + 24];
        float v0 = zs[(size_t)c0 * 8 + c];
        float v1 = zs[(size_t)c1 * 8 + c];
        float v2 = zs[(size_t)c2 * 8 + c];
        float v3 = zs[(size_t)c3 * 8 + c];
        acc += v0;
        acc += v1;
        acc += v2;
        acc += v3;
    }
    for (; e + 8 < e1; e += 16) {
        int c0 = col[e];
        int c1 = col[e + 8];
        float v0 = zs[(size_t)c0 * 8 + c];
        float v1 = zs[(size_t)c1 * 8 + c];
        acc += v0;
        acc += v1;
    }
    if (e < e1) acc += zs[(size_t)col[e] * 8 + c];
    acc += __shfl_xor(acc, 8);
    acc += __shfl_xor(acc, 16);
    acc += __shfl_xor(acc, 32);
    float o = dinv[node] * (acc + zs[(size_t)node * 8 + c]) + ((c < NCLS) ? b2[c] : 0.f);
    float val = (c < NCLS) ? o : -INFINITY;
    float m = val;
    m = fmaxf(m, __shfl_xor(m, 1));
    m = fmaxf(m, __shfl_xor(m, 2));
    m = fmaxf(m, __shfl_xor(m, 4));
    float ex = (c < NCLS) ? expf(o - m) : 0.f;
    float ss = ex;
    ss += __shfl_xor(ss, 1);
    ss += __shfl_xor(ss, 2);
    ss += __shfl_xor(ss, 4);
    if (eo == 0 && c < NCLS) out[(size_t)node * NCLS + c] = o - m - logf(ss);
}

extern "C" void kernel_launch(void* const* d_in, const int* in_sizes, int n_in,
                              void* d_out, int out_size, void* d_ws, size_t ws_size,
                              hipStream_t stream) {
    const float* x  = (const float*)d_in[0];
    const int*   ei = (const int*)d_in[1];
    const float* W1 = (const float*)d_in[2];
    const float* b1 = (const float*)d_in[3];
    const float* Wl = (const float*)d_in[4];
    const float* bl = (const float*)d_in[5];
    const float* W2 = (const float*)d_in[6];
    const float* b2 = (const float*)d_in[7];
    float* out = (float*)d_out;

    int*   wsI = (int*)d_ws;
    float* wsF = (float*)d_ws;
    int*          bcur   = wsI + OFF_BCUR;
    int*          rp     = wsI + OFF_RP;
    int*          deg    = wsI + OFF_DEG;
    float*        dinv   = wsF + OFF_DINV;
    int*          col    = wsI + OFF_COL;
    unsigned int* binned = (unsigned int*)(wsI + OFF_BINNED);
    float*        h0s    = wsF + OFF_H0;
    float*        zs     = wsF + OFF_Z;

    const int* src = ei;
    const int* dst = ei + N_EDGES;

    hipMemsetAsync(bcur, 0, NBUCK * sizeof(int), stream);

    k_bin<<<A3_BLOCKS, BIN_T, 0, stream>>>(src, dst, bcur, binned);
    k_csr<<<NBUCK, 512, 0, stream>>>(binned, bcur, rp, deg, dinv, col);
    k_xw1<<<XWN_BLOCKS, 256, 0, stream>>>(x, W1, dinv, h0s);
    k_agg1hops<<<(N_NODES * 64 + 255) / 256, 256, 0, stream>>>(h0s, rp, deg, col, dinv,
                                                               b1, Wl, bl, W2, zs);
    k_agg2<<<(N_NODES * 64 + 255) / 256, 256, 0, stream>>>(zs, rp, deg, col, dinv, b2, out);
}

// Round 12
// 525.899 us; speedup vs baseline: 1.2252x; 1.2252x over previous
//
#include <hip/hip_runtime.h>
#include <math.h>

#define N_NODES 100000
#define N_EDGES 3200000
#define F_IN    512
#define HID     16
#define NCLS    7
#define ALPHA   0.1f
#define K_HOPS  10

// bucketing: 128 nodes per bucket, fixed per-bucket slab (no histogram/scan pass)
#define SHIFT   7
#define BWIDTH  128
#define NBUCK   ((N_NODES + BWIDTH - 1) / BWIDTH)   // 782
#define SLAB    5120        // capacity per bucket: mean 4096 + 16 sigma (uniform dst)
#define CHUNK   4096
#define BIN_T   512
#define EPT     (CHUNK / BIN_T)                      // 8
#define A3_BLOCKS ((N_EDGES + CHUNK - 1) / CHUNK)   // 782

// ---- workspace layout (4-byte element offsets); no aliasing ----
#define OFF_BCUR    0u          // int[782]   per-bucket fill counters (memset 0)
#define OFF_RP      1024u       // int[100000] slab-global edge start per node
#define OFF_DEG     101376u     // int[100000]
#define OFF_DINV    201728u     // float[100000]
#define OFF_COL     302080u     // int[782*5120 = 4003840]
#define OFF_BINNED  4305920u    // uint[4003840]
#define OFF_H0      8309760u    // float[100000*16]
#define OFF_Z       9909760u    // float[100000*8]

// ---------------- bin: slab append of packed edges ----------------
__global__ void __launch_bounds__(BIN_T)
k_bin(const int* __restrict__ src, const int* __restrict__ dst,
      int* __restrict__ bcur, unsigned int* __restrict__ binned) {
    __shared__ int ha[NBUCK];
    __shared__ int gbase[NBUCK];
    __shared__ int lcur[NBUCK];
    int tid = threadIdx.x;
    int e0 = blockIdx.x * CHUNK;
    int e1 = e0 + CHUNK;
    if (e1 > N_EDGES) e1 = N_EDGES;
    for (int i = tid; i < NBUCK; i += BIN_T) ha[i] = 0;
    __syncthreads();
    int dloc[EPT];
#pragma unroll
    for (int i = 0; i < EPT; i++) {
        int e = e0 + tid + i * BIN_T;
        dloc[i] = (e < e1) ? dst[e] : -1;
        if (dloc[i] >= 0) atomicAdd(&ha[dloc[i] >> SHIFT], 1);
    }
    __syncthreads();
    for (int s = tid; s < NBUCK; s += BIN_T) {
        int c = ha[s];
        lcur[s] = 0;
        gbase[s] = c ? (s * SLAB + atomicAdd(&bcur[s], c)) : 0;
    }
    __syncthreads();
#pragma unroll
    for (int i = 0; i < EPT; i++) {
        int d = dloc[i];
        if (d >= 0) {
            int e = e0 + tid + i * BIN_T;
            int bk = d >> SHIFT;
            int idx = atomicAdd(&lcur[bk], 1);
            int pos = gbase[bk] + idx;
            if (pos < (int)(NBUCK * SLAB))             // slab overflow guard
                binned[pos] =
                    ((unsigned int)(d & (BWIDTH - 1)) << 17) | (unsigned int)src[e];
        }
    }
}

// ---------------- csr: per-bucket count, local scan, rp/deg/dinv, col scatter ----------------
__global__ void __launch_bounds__(512)
k_csr(const unsigned int* __restrict__ binned, const int* __restrict__ bcur,
      int* __restrict__ rp, int* __restrict__ deg, float* __restrict__ dinv,
      int* __restrict__ col) {
    __shared__ int cnt[BWIDTH];
    __shared__ int s[BWIDTH];
    __shared__ int cur[BWIDTH];
    int tid = threadIdx.x;
    int b = blockIdx.x;
    int base = b << SHIFT;
    int e0 = b * SLAB;
    int fill = bcur[b];
    if (fill > SLAB) fill = SLAB;                     // overflow clamp
    int e1 = e0 + fill;
    if (tid < BWIDTH) cnt[tid] = 0;
    __syncthreads();
    for (int e = e0 + tid; e < e1; e += 512)
        atomicAdd(&cnt[binned[e] >> 17], 1);
    __syncthreads();
    int v = 0;
    if (tid < BWIDTH) { v = cnt[tid]; s[tid] = v; }
    __syncthreads();
    for (int off = 1; off < BWIDTH; off <<= 1) {
        int t = 0;
        if (tid < BWIDTH && tid >= off) t = s[tid - off];
        __syncthreads();
        if (tid < BWIDTH) s[tid] += t;
        __syncthreads();
    }
    if (tid < BWIDTH) {
        int ex = s[tid] - v;
        cur[tid] = ex;
        int node = base + tid;
        if (node < N_NODES) {
            rp[node] = e0 + ex;
            deg[node] = v;
            dinv[node] = rsqrtf((float)(v + 1));
        }
    }
    __syncthreads();
    for (int e = e0 + tid; e < e1; e += 512) {
        unsigned int w = binned[e];
        int ln = (int)(w >> 17);
        int p = atomicAdd(&cur[ln], 1);
        col[e0 + p] = (int)(w & 0x1FFFFu);
    }
}

// ---------------- h0s = dinv * (x @ W1): wave-per-node, 2-deep prefetch ----------------
#define XWN_BLOCKS 512
#define XWN_WAVES  (XWN_BLOCKS * 4)   // 2048

__device__ __forceinline__ float4 shfl4_xor(float4 v, int m) {
    float4 r;
    r.x = __shfl_xor(v.x, m);
    r.y = __shfl_xor(v.y, m);
    r.z = __shfl_xor(v.z, m);
    r.w = __shfl_xor(v.w, m);
    return r;
}
__device__ __forceinline__ float4 add4(float4 a, float4 b) {
    a.x += b.x; a.y += b.y; a.z += b.z; a.w += b.w;
    return a;
}

__global__ void __launch_bounds__(256)
k_xw1(const float* __restrict__ x, const float* __restrict__ W,
      const float* __restrict__ dinv, float* __restrict__ h0s) {
    int lane = threadIdx.x & 63;
    int wid = (blockIdx.x * 256 + threadIdx.x) >> 6;   // 0..2047

    float4 w[32];
    const float4* W4 = (const float4*)W;
#pragma unroll
    for (int j = 0; j < 8; j++) {
#pragma unroll
        for (int q = 0; q < 4; q++)
            w[j * 4 + q] = W4[(8 * lane + j) * 4 + q];
    }

    float4 z4 = make_float4(0.f, 0.f, 0.f, 0.f);
    int node = wid;
    float4 xc0 = z4, xc1 = z4, xn0 = z4, xn1 = z4;     // no uninitialized reads
    if (node < N_NODES) {
        const float4* xr = (const float4*)(x + (size_t)node * F_IN) + 2 * lane;
        xc0 = xr[0];
        xc1 = xr[1];
    }
    int n1 = node + XWN_WAVES;
    if (n1 < N_NODES) {
        const float4* xr = (const float4*)(x + (size_t)n1 * F_IN) + 2 * lane;
        xn0 = xr[0];
        xn1 = xr[1];
    }

    for (; node < N_NODES; node += XWN_WAVES) {
        int n2 = node + 2 * XWN_WAVES;
        float4 xp0 = z4, xp1 = z4;
        if (n2 < N_NODES) {
            const float4* xr = (const float4*)(x + (size_t)n2 * F_IN) + 2 * lane;
            xp0 = xr[0];
            xp1 = xr[1];
        }

        float xa0 = xc0.x, xa1 = xc0.y, xa2 = xc0.z, xa3 = xc0.w;
        float xa4 = xc1.x, xa5 = xc1.y, xa6 = xc1.z, xa7 = xc1.w;

        float4 pp0 = z4, pp1 = z4, pp2 = z4, pp3 = z4;
#define XW_FMA(J, XA)                                            \
        pp0.x += XA * w[J*4+0].x; pp0.y += XA * w[J*4+0].y;      \
        pp0.z += XA * w[J*4+0].z; pp0.w += XA * w[J*4+0].w;      \
        pp1.x += XA * w[J*4+1].x; pp1.y += XA * w[J*4+1].y;      \
        pp1.z += XA * w[J*4+1].z; pp1.w += XA * w[J*4+1].w;      \
        pp2.x += XA * w[J*4+2].x; pp2.y += XA * w[J*4+2].y;      \
        pp2.z += XA * w[J*4+2].z; pp2.w += XA * w[J*4+2].w;      \
        pp3.x += XA * w[J*4+3].x; pp3.y += XA * w[J*4+3].y;      \
        pp3.z += XA * w[J*4+3].z; pp3.w += XA * w[J*4+3].w;
        XW_FMA(0, xa0) XW_FMA(1, xa1) XW_FMA(2, xa2) XW_FMA(3, xa3)
        XW_FMA(4, xa4) XW_FMA(5, xa5) XW_FMA(6, xa6) XW_FMA(7, xa7)
#undef XW_FMA

        int b5 = (lane >> 5) & 1;
        float4 k0 = b5 ? pp2 : pp0;
        float4 k1 = b5 ? pp3 : pp1;
        float4 s0 = b5 ? pp0 : pp2;
        float4 s1 = b5 ? pp1 : pp3;
        k0 = add4(k0, shfl4_xor(s0, 32));
        k1 = add4(k1, shfl4_xor(s1, 32));

        int b4 = (lane >> 4) & 1;
        float4 kk = b4 ? k1 : k0;
        float4 ss = b4 ? k0 : k1;
        kk = add4(kk, shfl4_xor(ss, 16));

        int b3 = (lane >> 3) & 1;
        float e0 = b3 ? kk.z : kk.x;
        float e1 = b3 ? kk.w : kk.y;
        float f0 = b3 ? kk.x : kk.z;
        float f1 = b3 ? kk.y : kk.w;
        e0 += __shfl_xor(f0, 8);
        e1 += __shfl_xor(f1, 8);

        int b2 = (lane >> 2) & 1;
        float v = b2 ? e1 : e0;
        float sv = b2 ? e0 : e1;
        v += __shfl_xor(sv, 4);

        v += __shfl_xor(v, 1);
        v += __shfl_xor(v, 2);

        if ((lane & 3) == 0) {
            float dv = dinv[node];
            h0s[(size_t)node * HID + (lane >> 2)] = dv * v;
        }

        xc0 = xn0; xc1 = xn1;
        xn0 = xp0; xn1 = xp1;
    }
}

// ---------------- aggregate 1 + 10 hops + W2 projection (4 nodes / wave) ----------------
// Each 16-lane group owns one node (c = lane&15).  Agg: 4 reg-accumulators,
// 4 independent gathers in flight per group; per-acc edge order and final
// (a0+a1)+(a2+a3) combine bitwise-match the old eo-butterfly.  Hops: Wl/W2
// columns preloaded to 16+16 static regs; shfl chain serves 4 nodes at once.
__global__ void __launch_bounds__(256)
k_agg1hops(const float* __restrict__ h0s, const int* __restrict__ rp,
           const int* __restrict__ deg, const int* __restrict__ col,
           const float* __restrict__ dinv, const float* __restrict__ b1,
           const float* __restrict__ Wl, const float* __restrict__ bl,
           const float* __restrict__ W2, float* __restrict__ zs) {
    int lane = threadIdx.x & 63;
    int grp = lane >> 4;                               // 0..3
    int c = lane & 15;
    int node = ((blockIdx.x * 256 + threadIdx.x) >> 6) * 4 + grp;
    if (node >= N_NODES) return;                       // uniform per group

    int e0 = rp[node];
    int dg = deg[node];
    if (dg < 0) dg = 0;
    if (dg > SLAB) dg = SLAB;                          // defensive clamp
    int e1 = e0 + dg;

    float acc0 = 0.f, acc1 = 0.f, acc2 = 0.f, acc3 = 0.f;
    for (int e = e0; e < e1; e += 4) {
        int c0 = col[e];
        bool m1 = (e + 1 < e1), m2 = (e + 2 < e1), m3 = (e + 3 < e1);
        int c1 = m1 ? col[e + 1] : 0;
        int c2 = m2 ? col[e + 2] : 0;
        int c3 = m3 ? col[e + 3] : 0;
        float v0 = h0s[(size_t)c0 * HID + c];
        float v1 = m1 ? h0s[(size_t)c1 * HID + c] : 0.f;
        float v2 = m2 ? h0s[(size_t)c2 * HID + c] : 0.f;
        float v3 = m3 ? h0s[(size_t)c3 * HID + c] : 0.f;
        acc0 += v0;
        acc1 += v1;
        acc2 += v2;
        acc3 += v3;
    }
    float acc = (acc0 + acc1) + (acc2 + acc3);

    float dv = dinv[node];
    float o = dv * (acc + h0s[(size_t)node * HID + c]) + b1[c];
    float h = fmaxf(o, 0.f);

    // preload Wl column c and W2 column c (static-indexed regs)
    float w[HID], w2[HID];
#pragma unroll
    for (int k = 0; k < HID; k++) w[k] = Wl[k * HID + c];
#pragma unroll
    for (int k = 0; k < HID; k++) w2[k] = (c < NCLS) ? W2[k * NCLS + c] : 0.f;
    float blc = bl[c];

    int bs = lane & 48;                                // group base for shfl
    for (int it = 0; it < K_HOPS; it++) {
        float tm = blc;
#pragma unroll
        for (int k = 0; k < HID; k++) {
            float hk = __shfl(h, bs + k);
            tm += hk * w[k];
        }
        h = ALPHA * fmaxf(tm, 0.f) + (1.f - ALPHA) * h;
    }

    float zz = 0.f;
#pragma unroll
    for (int k = 0; k < HID; k++) {
        float hk = __shfl(h, bs + k);
        zz += hk * w2[k];
    }
    if (c < 8) zs[(size_t)node * 8 + c] = dv * zz;     // c==7 -> +0
}

// ---------------- aggregate 2 + log_softmax: one wave per node, x4 unroll ----------------
__global__ void k_agg2(const float* __restrict__ zs, const int* __restrict__ rp,
                       const int* __restrict__ deg, const int* __restrict__ col,
                       const float* __restrict__ dinv, const float* __restrict__ b2,
                       float* __restrict__ out) {
    int node = (blockIdx.x * blockDim.x + threadIdx.x) >> 6;
    if (node >= N_NODES) return;
    int lane = threadIdx.x & 63;
    int c = lane & 7, eo = lane >> 3;
    int e0 = rp[node];
    int dg = deg[node];
    if (dg < 0) dg = 0;
    if (dg > SLAB) dg = SLAB;                          // defensive clamp
    int e1 = e0 + dg;
    float acc = 0.f;
    int e = e0 + eo;
    for (; e + 24 < e1; e += 32) {
        int c0 = col[e];
        int c1 = col[e + 8];
        int c2 = col[e + 16];
        int c3 = col[e + 24];
        float v0 = zs[(size_t)c0 * 8 + c];
        float v1 = zs[(size_t)c1 * 8 + c];
        float v2 = zs[(size_t)c2 * 8 + c];
        float v3 = zs[(size_t)c3 * 8 + c];
        acc += v0;
        acc += v1;
        acc += v2;
        acc += v3;
    }
    for (; e + 8 < e1; e += 16) {
        int c0 = col[e];
        int c1 = col[e + 8];
        float v0 = zs[(size_t)c0 * 8 + c];
        float v1 = zs[(size_t)c1 * 8 + c];
        acc += v0;
        acc += v1;
    }
    if (e < e1) acc += zs[(size_t)col[e] * 8 + c];
    acc += __shfl_xor(acc, 8);
    acc += __shfl_xor(acc, 16);
    acc += __shfl_xor(acc, 32);
    float o = dinv[node] * (acc + zs[(size_t)node * 8 + c]) + ((c < NCLS) ? b2[c] : 0.f);
    float val = (c < NCLS) ? o : -INFINITY;
    float m = val;
    m = fmaxf(m, __shfl_xor(m, 1));
    m = fmaxf(m, __shfl_xor(m, 2));
    m = fmaxf(m, __shfl_xor(m, 4));
    float ex = (c < NCLS) ? expf(o - m) : 0.f;
    float ss = ex;
    ss += __shfl_xor(ss, 1);
    ss += __shfl_xor(ss, 2);
    ss += __shfl_xor(ss, 4);
    if (eo == 0 && c < NCLS) out[(size_t)node * NCLS + c] = o - m - logf(ss);
}

extern "C" void kernel_launch(void* const* d_in, const int* in_sizes, int n_in,
                              void* d_out, int out_size, void* d_ws, size_t ws_size,
                              hipStream_t stream) {
    const float* x  = (const float*)d_in[0];
    const int*   ei = (const int*)d_in[1];
    const float* W1 = (const float*)d_in[2];
    const float* b1 = (const float*)d_in[3];
    const float* Wl = (const float*)d_in[4];
    const float* bl = (const float*)d_in[5];
    const float* W2 = (const float*)d_in[6];
    const float* b2 = (const float*)d_in[7];
    float* out = (float*)d_out;

    int*   wsI = (int*)d_ws;
    float* wsF = (float*)d_ws;
    int*          bcur   = wsI + OFF_BCUR;
    int*          rp     = wsI + OFF_RP;
    int*          deg    = wsI + OFF_DEG;
    float*        dinv   = wsF + OFF_DINV;
    int*          col    = wsI + OFF_COL;
    unsigned int* binned = (unsigned int*)(wsI + OFF_BINNED);
    float*        h0s    = wsF + OFF_H0;
    float*        zs     = wsF + OFF_Z;

    const int* src = ei;
    const int* dst = ei + N_EDGES;

    hipMemsetAsync(bcur, 0, NBUCK * sizeof(int), stream);

    k_bin<<<A3_BLOCKS, BIN_T, 0, stream>>>(src, dst, bcur, binned);
    k_csr<<<NBUCK, 512, 0, stream>>>(binned, bcur, rp, deg, dinv, col);
    k_xw1<<<XWN_BLOCKS, 256, 0, stream>>>(x, W1, dinv, h0s);
    k_agg1hops<<<(N_NODES / 4 * 64) / 256, 256, 0, stream>>>(h0s, rp, deg, col, dinv,
                                                             b1, Wl, bl, W2, zs);
    k_agg2<<<(N_NODES * 64 + 255) / 256, 256, 0, stream>>>(zs, rp, deg, col, dinv, b2, out);
}